// Round 1
// baseline (993.308 us; speedup 1.0000x reference)
//
#include <hip/hip_runtime.h>

// Problem constants (B, E, D fixed by the reference)
#define BATCH 16384
#define NEXP 12
#define DIM 768
#define GATE_DIM (2*DIM)          // 1536
#define ROW4 (NEXP*DIM/4)         // audio/image row stride in float4 = 2304
#define G4 (GATE_DIM/4)           // 384 float4 per gate row
#define D4 (DIM/4)                // 192 float4 per modality chunk
#define R 8                       // batch rows per block
#define BLK 256

__global__ __launch_bounds__(BLK) void gate_fused_kernel(
    const float* __restrict__ audio, const float* __restrict__ image,
    const float* __restrict__ Wa,    const float* __restrict__ ba,
    const float* __restrict__ Wi,    const float* __restrict__ bi,
    const float* __restrict__ ga,    const float* __restrict__ gi,
    float* __restrict__ out)
{
    __shared__ float4 gate4[R * G4];      // 48 KB: 8 gate rows of 1536 floats
    __shared__ float  slog[R * 24];       // logits per row (12 audio + 12 image)
    __shared__ int    sidx[R * 2];        // argmax per (row, modality)

    const int tid   = threadIdx.x;
    const int bBase = blockIdx.x * R;

    const float4* av4 = (const float4*)audio;
    const float4* iv4 = (const float4*)image;

    // ---- Phase 1: stage 8 gate rows (concat audio[b,0,:], image[b,0,:]) into LDS
    for (int u = tid; u < R * G4; u += BLK) {
        int r = u / G4, j4 = u % G4;
        size_t row = (size_t)(bBase + r) * ROW4;
        float4 v = (j4 < D4) ? av4[row + j4] : iv4[row + (j4 - D4)];
        gate4[r * G4 + j4] = v;
    }
    __syncthreads();

    // ---- Phase 2: 24 logits x 8 rows. Wave w computes logits [6w, 6w+6).
    const int wave = tid >> 6, lane = tid & 63;
    const float4* Wv = (const float4*)((wave < 2) ? Wa : Wi) + ((wave & 1) * 6) * G4;

    float acc[6][R];
#pragma unroll
    for (int i = 0; i < 6; ++i)
#pragma unroll
        for (int r = 0; r < R; ++r) acc[i][r] = 0.0f;

#pragma unroll
    for (int k4 = 0; k4 < 6; ++k4) {
        int j4 = lane + 64 * k4;          // 0..383
        float4 w[6];
#pragma unroll
        for (int i = 0; i < 6; ++i) w[i] = Wv[i * G4 + j4];
#pragma unroll
        for (int r = 0; r < R; ++r) {
            float4 x = gate4[r * G4 + j4];
#pragma unroll
            for (int i = 0; i < 6; ++i) {
                acc[i][r] += w[i].x * x.x;
                acc[i][r] += w[i].y * x.y;
                acc[i][r] += w[i].z * x.z;
                acc[i][r] += w[i].w * x.w;
            }
        }
    }

    // butterfly reduce each (i,r) across the 64 lanes
#pragma unroll
    for (int i = 0; i < 6; ++i)
#pragma unroll
        for (int r = 0; r < R; ++r) {
            float v = acc[i][r];
            v += __shfl_xor(v, 32);
            v += __shfl_xor(v, 16);
            v += __shfl_xor(v, 8);
            v += __shfl_xor(v, 4);
            v += __shfl_xor(v, 2);
            v += __shfl_xor(v, 1);
            acc[i][r] = v;
        }
    if (lane == 0) {
#pragma unroll
        for (int r = 0; r < R; ++r)
#pragma unroll
            for (int i = 0; i < 6; ++i)
                slog[r * 24 + wave * 6 + i] = acc[i][r];
    }
    __syncthreads();

    // ---- Phase 3: argmax(logits + bias + gumbel) per (row, modality) in fp32
    if (tid < R * 2) {
        int r = tid >> 1, m = tid & 1;
        const float* bb = m ? bi : ba;
        const float* gg = m ? gi : ga;
        size_t gb = (size_t)(bBase + r) * NEXP;
        float best = -3.4e38f;
        int bidx = 0;
        for (int e = 0; e < NEXP; ++e) {
            float z = slog[r * 24 + m * NEXP + e] + bb[e] + gg[gb + e];
            if (z > best) { best = z; bidx = e; }   // strict >: np.argmax first-max
        }
        sidx[r * 2 + m] = bidx;
    }
    __syncthreads();

    // ---- Phase 4a: write one-hot ret_a / ret_i
    float* ret = out + (size_t)BATCH * GATE_DIM;
    if (tid < R * 24) {
        int r = tid / 24, c = tid % 24, m = c / NEXP, e = c % NEXP;
        size_t b = (size_t)(bBase + r);
        ret[(size_t)m * BATCH * NEXP + b * NEXP + e] =
            (sidx[r * 2 + m] == e) ? 1.0f : 0.0f;
    }

    // ---- Phase 4b: gather selected expert row, scale by 1/12, store
    float4* outv = (float4*)out;
    const float s = 1.0f / 12.0f;
    for (int u = tid; u < R * 2 * D4; u += BLK) {
        int r = u / (2 * D4), w = u % (2 * D4), m = w / D4, j = w % D4;
        size_t b = (size_t)(bBase + r);
        const float4* src = m ? iv4 : av4;
        float4 v = src[b * ROW4 + (size_t)sidx[r * 2 + m] * D4 + j];
        v.x *= s; v.y *= s; v.z *= s; v.w *= s;
        outv[b * (G4) + m * D4 + j] = v;
    }
}

extern "C" void kernel_launch(void* const* d_in, const int* in_sizes, int n_in,
                              void* d_out, int out_size, void* d_ws, size_t ws_size,
                              hipStream_t stream) {
    const float* audio = (const float*)d_in[0];
    const float* image = (const float*)d_in[1];
    const float* Wa    = (const float*)d_in[2];
    const float* ba    = (const float*)d_in[3];
    const float* Wi    = (const float*)d_in[4];
    const float* bi    = (const float*)d_in[5];
    const float* ga    = (const float*)d_in[6];
    const float* gi    = (const float*)d_in[7];
    float* out = (float*)d_out;

    dim3 grid(BATCH / R), block(BLK);
    gate_fused_kernel<<<grid, block, 0, stream>>>(audio, image, Wa, ba, Wi, bi,
                                                  ga, gi, out);
}

// Round 2
// 976.912 us; speedup vs baseline: 1.0168x; 1.0168x over previous
//
#include <hip/hip_runtime.h>

typedef float v4f __attribute__((ext_vector_type(4)));

// Problem constants (B, E, D fixed by the reference)
#define BATCH 16384
#define NEXP 12
#define DIM 768
#define GATE_DIM (2*DIM)          // 1536
#define ROW4 (NEXP*DIM/4)         // audio/image row stride in float4 = 2304
#define G4 (GATE_DIM/4)           // 384 float4 per gate row
#define D4 (DIM/4)                // 192 float4 per modality chunk
#define R 4                       // batch rows per block (24 KB LDS -> 6 blocks/CU)
#define BLK 256

__global__ __launch_bounds__(BLK) void gate_fused_kernel(
    const float* __restrict__ audio, const float* __restrict__ image,
    const float* __restrict__ Wa,    const float* __restrict__ ba,
    const float* __restrict__ Wi,    const float* __restrict__ bi,
    const float* __restrict__ ga,    const float* __restrict__ gi,
    float* __restrict__ out)
{
    __shared__ v4f   gate4[R * G4];       // 24 KB: 4 gate rows of 1536 floats
    __shared__ float slog[R * 24];        // logits per row (12 audio + 12 image)
    __shared__ int   sidx[R * 2];         // argmax per (row, modality)

    const int tid   = threadIdx.x;
    const int bBase = blockIdx.x * R;

    const v4f* av4 = (const v4f*)audio;
    const v4f* iv4 = (const v4f*)image;

    // ---- Phase 1: stage gate rows (concat audio[b,0,:], image[b,0,:]) into LDS
    for (int u = tid; u < R * G4; u += BLK) {
        int r = u / G4, j4 = u % G4;
        size_t row = (size_t)(bBase + r) * ROW4;
        v4f v = (j4 < D4) ? av4[row + j4] : iv4[row + (j4 - D4)];
        gate4[r * G4 + j4] = v;
    }
    __syncthreads();

    // ---- Phase 2: 24 logits x R rows. Wave w computes logits [6w, 6w+6).
    const int wave = tid >> 6, lane = tid & 63;
    const v4f* __restrict__ Wv =
        (const v4f*)((wave < 2) ? Wa : Wi) + ((wave & 1) * 6) * G4;

    float acc[6][R];
#pragma unroll
    for (int i = 0; i < 6; ++i)
#pragma unroll
        for (int r = 0; r < R; ++r) acc[i][r] = 0.0f;

    for (int k4 = 0; k4 < 6; ++k4) {       // not unrolled: keep live set small
        int j4 = lane + 64 * k4;            // 0..383
        v4f w[6];
#pragma unroll
        for (int i = 0; i < 6; ++i) w[i] = Wv[i * G4 + j4];
#pragma unroll
        for (int r = 0; r < R; ++r) {
            v4f x = gate4[r * G4 + j4];
#pragma unroll
            for (int i = 0; i < 6; ++i) {
                acc[i][r] += w[i].x * x.x;
                acc[i][r] += w[i].y * x.y;
                acc[i][r] += w[i].z * x.z;
                acc[i][r] += w[i].w * x.w;
            }
        }
    }

    // butterfly reduce each (i,r) across the 64 lanes
#pragma unroll
    for (int i = 0; i < 6; ++i)
#pragma unroll
        for (int r = 0; r < R; ++r) {
            float v = acc[i][r];
            v += __shfl_xor(v, 32);
            v += __shfl_xor(v, 16);
            v += __shfl_xor(v, 8);
            v += __shfl_xor(v, 4);
            v += __shfl_xor(v, 2);
            v += __shfl_xor(v, 1);
            acc[i][r] = v;
        }
    if (lane == 0) {
#pragma unroll
        for (int r = 0; r < R; ++r)
#pragma unroll
            for (int i = 0; i < 6; ++i)
                slog[r * 24 + wave * 6 + i] = acc[i][r];
    }
    __syncthreads();

    // ---- Phase 3: argmax(logits + bias + gumbel) per (row, modality) in fp32
    if (tid < R * 2) {
        int r = tid >> 1, m = tid & 1;
        const float* bb = m ? bi : ba;
        const float* gg = m ? gi : ga;
        size_t gb = (size_t)(bBase + r) * NEXP;
        float best = -3.4e38f;
        int bidx = 0;
        for (int e = 0; e < NEXP; ++e) {
            float z = slog[r * 24 + m * NEXP + e] + bb[e] + gg[gb + e];
            if (z > best) { best = z; bidx = e; }   // strict >: np.argmax first-max
        }
        sidx[r * 2 + m] = bidx;
    }
    __syncthreads();

    // ---- Phase 4a: write one-hot ret_a / ret_i
    float* ret = out + (size_t)BATCH * GATE_DIM;
    if (tid < R * 24) {
        int r = tid / 24, c = tid % 24, m = c / NEXP, e = c % NEXP;
        size_t b = (size_t)(bBase + r);
        ret[(size_t)m * BATCH * NEXP + b * NEXP + e] =
            (sidx[r * 2 + m] == e) ? 1.0f : 0.0f;
    }

    // ---- Phase 4b: gather selected expert row, scale by 1/12, store (streaming)
    v4f* outv = (v4f*)out;
    const float s = 1.0f / 12.0f;
    for (int u = tid; u < R * 2 * D4; u += BLK) {
        int r = u / (2 * D4), w = u % (2 * D4), m = w / D4, j = w % D4;
        size_t b = (size_t)(bBase + r);
        const v4f* src = m ? iv4 : av4;
        v4f v = __builtin_nontemporal_load(
            &src[b * ROW4 + (size_t)sidx[r * 2 + m] * D4 + j]);
        v *= s;
        __builtin_nontemporal_store(v, &outv[b * G4 + m * D4 + j]);
    }
}

extern "C" void kernel_launch(void* const* d_in, const int* in_sizes, int n_in,
                              void* d_out, int out_size, void* d_ws, size_t ws_size,
                              hipStream_t stream) {
    const float* audio = (const float*)d_in[0];
    const float* image = (const float*)d_in[1];
    const float* Wa    = (const float*)d_in[2];
    const float* ba    = (const float*)d_in[3];
    const float* Wi    = (const float*)d_in[4];
    const float* bi    = (const float*)d_in[5];
    const float* ga    = (const float*)d_in[6];
    const float* gi    = (const float*)d_in[7];
    float* out = (float*)d_out;

    dim3 grid(BATCH / R), block(BLK);
    gate_fused_kernel<<<grid, block, 0, stream>>>(audio, image, Wa, ba, Wi, bi,
                                                  ga, gi, out);
}